// Round 11
// baseline (100.196 us; speedup 1.0000x reference)
//
#include <hip/hip_runtime.h>
#include <hip/hip_bf16.h>

typedef __bf16 bf16_t;
typedef __bf16 bf16x8 __attribute__((ext_vector_type(8)));
typedef __bf16 bf16x4 __attribute__((ext_vector_type(4)));
typedef short short4v __attribute__((ext_vector_type(4)));
typedef float f32x4 __attribute__((ext_vector_type(4)));

static_assert(sizeof(bf16x8) == 16, "bf16x8 must be 16B");

// Problem constants
#define BB 2
#define SS 2048
#define DD 512
#define HH 8
#define DH 64
#define LOG2E 1.44269504088896f
// HID == 512; head block = contiguous [2048,64] at (b*8+h)*131072 (flat view).
// Reshape semantics: flat intra-batch off = s*512 + n  <->  h = s>>8,
// t = (s&255)*8 + (n>>6), d = n&63.  (Q/K/attn/combine all use the flat view.)

// ------------- prep: z=0..2 cast q/k/v f32->bf16; z=3 transpose+cast weights -------------
__global__ void prep(const float* __restrict__ q, const float* __restrict__ k,
                     const float* __restrict__ v, const float* __restrict__ w0,
                     const float* __restrict__ w1, const float* __restrict__ w2,
                     const float* __restrict__ w3, bf16_t* __restrict__ qkvb,
                     bf16_t* __restrict__ wt, int n) {
  const int tid = threadIdx.x;
  if (blockIdx.z < 3) {
    const float* src = (blockIdx.z == 0) ? q : (blockIdx.z == 1) ? k : v;
    bf16_t* out = qkvb + (size_t)blockIdx.z * n;
    int i = (blockIdx.x * 256 + tid) * 8;
    if (i >= n) return;
    const float4* s4 = (const float4*)(src + i);
    float4 a = s4[0], b = s4[1];
    bf16x8 o;
    o[0] = (bf16_t)a.x; o[1] = (bf16_t)a.y; o[2] = (bf16_t)a.z; o[3] = (bf16_t)a.w;
    o[4] = (bf16_t)b.x; o[5] = (bf16_t)b.y; o[6] = (bf16_t)b.z; o[7] = (bf16_t)b.w;
    *(bf16x8*)(out + i) = o;
  } else {
    // transpose+cast: Wt[nn][kk] = (bf16)W[kk][nn]
    __shared__ float tile[32][33];
    const int x = blockIdx.x;                  // 0..1023
    const int wsel = x >> 8;
    const int nb = ((x >> 4) & 15) * 32, kb = (x & 15) * 32;
    const int tx = tid & 31, ty = tid >> 5;    // (32,8)
    const float* W = (wsel == 0) ? w0 : (wsel == 1) ? w1 : (wsel == 2) ? w2 : w3;
    bf16_t* out = wt + (size_t)wsel * 512 * 512;
#pragma unroll
    for (int i = 0; i < 4; i++)
      tile[ty + i * 8][tx] = W[(size_t)(kb + ty + i * 8) * 512 + nb + tx];
    __syncthreads();
#pragma unroll
    for (int i = 0; i < 4; i++)
      out[(size_t)(nb + ty + i * 8) * 512 + kb + tx] = (bf16_t)tile[tx][ty + i * 8];
  }
}

// ------------- GEMM: C[M,N] = (A[M,K] @ Bt[N,K]^T + bias[N]) * (z==0 ? s0 : 1) ----------
// Templated tile: BM x BN, BK=64, 256 thr, 4 waves 2x2. global_load_lds(16B), dbuf LDS.
// TMODE=1: z==2 slice is scattered into Tbase = vtp[bh][32 kv-tiles][64d x 64kv,
// XOR-swizzled bytes: tile*8192 + d*128 + ((kv*2)^((d&7)<<4))] per the reshape
// semantics (h = s>>8, t = (s&255)*8 + (col>>6), d = col&63; t = tile*64+kv).
template <int BM, int BN, int WM, int WN, int TMODE, typename OutT>
__global__ __launch_bounds__(256) void gemm2(
    const bf16_t* __restrict__ Abase, const bf16_t* __restrict__ Btbase,
    const float* __restrict__ bias0, const float* __restrict__ bias1,
    const float* __restrict__ bias2, OutT* __restrict__ Cbase,
    bf16_t* __restrict__ Tbase,
    int M, int N, int K, long Az, long Bz, long Cz, float scale0) {
  static_assert(BM == 2 * WM && BN == 2 * WN, "2x2 wave grid");
  constexpr int FM = WM / 16, FN = WN / 16;
  constexpr int AJ = BM / 32, BJ = BN / 32;

  const bf16_t* A  = Abase + (size_t)blockIdx.z * Az;
  const bf16_t* Bt = Btbase + (size_t)blockIdx.z * Bz;
  const float* bias = (blockIdx.z == 0) ? bias0 : (blockIdx.z == 1) ? bias1 : bias2;
  OutT* C = Cbase + (size_t)blockIdx.z * Cz;
  const float osc = (blockIdx.z == 0) ? scale0 : 1.0f;

  __shared__ bf16_t As[2][BM * 64];
  __shared__ bf16_t Bs[2][BN * 64];

  const int tid = threadIdx.x, w = tid >> 6, l = tid & 63;
  const int bm = blockIdx.y, bn = blockIdx.x;
  const int wm0 = (w >> 1) * WM, wn0 = (w & 1) * WN;
  const int lr = l & 15, lg = l >> 4;

  f32x4 acc[FM][FN] = {};

  auto stage = [&](int buf, int kt) {
#pragma unroll
    for (int j = 0; j < AJ; j++) {
      int lin = j * 256 + tid;              // 16B-chunk index
      int row = lin >> 3, cc = lin & 7;
      const bf16_t* g = A + (size_t)(bm * BM + row) * K + kt * 64 + cc * 8;
      __builtin_amdgcn_global_load_lds(
          (const __attribute__((address_space(1))) void*)g,
          (__attribute__((address_space(3))) void*)(&As[buf][(j * 256 + w * 64) * 8]), 16, 0, 0);
    }
#pragma unroll
    for (int j = 0; j < BJ; j++) {
      int lin = j * 256 + tid;
      int row = lin >> 3, cc = lin & 7;
      const bf16_t* g = Bt + (size_t)(bn * BN + row) * K + kt * 64 + cc * 8;
      __builtin_amdgcn_global_load_lds(
          (const __attribute__((address_space(1))) void*)g,
          (__attribute__((address_space(3))) void*)(&Bs[buf][(j * 256 + w * 64) * 8]), 16, 0, 0);
    }
  };

  stage(0, 0);
  const int KT = K >> 6;
  for (int kt = 0; kt < KT; kt++) {
    __syncthreads();                         // drains vmcnt -> buf[kt&1] ready
    if (kt + 1 < KT) stage((kt + 1) & 1, kt + 1);
    const bf16_t* as = As[kt & 1];
    const bf16_t* bs = Bs[kt & 1];
#pragma unroll
    for (int kc = 0; kc < 2; kc++) {
      bf16x8 a[FM], b[FN];
#pragma unroll
      for (int i = 0; i < FM; i++)
        a[i] = *(const bf16x8*)(as + (wm0 + i * 16 + lr) * 64 + kc * 32 + lg * 8);
#pragma unroll
      for (int j = 0; j < FN; j++)
        b[j] = *(const bf16x8*)(bs + (wn0 + j * 16 + lr) * 64 + kc * 32 + lg * 8);
#pragma unroll
      for (int i = 0; i < FM; i++)
#pragma unroll
        for (int j = 0; j < FN; j++)
          acc[i][j] = __builtin_amdgcn_mfma_f32_16x16x32_bf16(a[i], b[j], acc[i][j], 0, 0, 0);
    }
  }

  // epilogue: C row = (lane>>4)*4+reg, col = lane&15 (verified m89/m91 layout)
  const int row0 = bm * BM + wm0, col0 = bn * BN + wn0;
  if (TMODE && blockIdx.z == 2) {
    // scatter V into pre-swizzled per-tile V^T buffer (see header comment).
    // BM=128-aligned tiles stay within one head (s-range [brow&2047, +128)).
    const int brow = bm * BM;
    char* vbase = (char*)(Tbase +
        (size_t)((brow >> 11) * 8 + ((brow & 2047) >> 8)) * (SS * DH));
    const int sbase = (brow & 255) + wm0 + lg * 4;   // s-local base (r adds, <=255)
#pragma unroll
    for (int j = 0; j < FN; j++) {
      int d = wn0 + j * 16 + lr;                     // col&63
      float bv = bias[bn * 64 + d];
      const int dsw = (d & 7) << 4;
      char* drow = vbase + d * 128;
#pragma unroll
      for (int i = 0; i < FM; i++) {
#pragma unroll
        for (int r = 0; r < 4; r++) {
          int s = sbase + i * 16 + r;
          int tile = s >> 3;                         // (s&255)>>3
          int kv = ((s & 7) << 3) | bn;              // t = tile*64 + kv
          *(bf16_t*)(drow + tile * 8192 + ((kv << 1) ^ dsw)) =
              (bf16_t)(acc[i][j][r] + bv);
        }
      }
    }
    return;
  }
#pragma unroll
  for (int j = 0; j < FN; j++) {
    int col = col0 + j * 16 + lr;
    float bv = bias[col];
#pragma unroll
    for (int i = 0; i < FM; i++) {
      int row = row0 + i * 16 + lg * 4;
#pragma unroll
      for (int r = 0; r < 4; r++) {
        float vv = (acc[i][j][r] + bv) * osc;
        C[(size_t)(row + r) * N + col] = (OutT)vv;
      }
    }
  }
}

// ------------- flash attention, KV-split x2; K (pre-swizzled src) AND V^T (linear,
// swizzle baked into vtp by the GEMM) staged via global_load_lds -> ZERO ds_writes.
// grid 1024: id -> bh low3 (XCD-affinity), bh hi, qt, half. 4 waves, QBLK=64, KVBLK=64.
// PV fragment reads / MFMAs byte-identical to R5/R7/R8-passed kernels.
// exp2-domain softmax (Q pre-scaled by log2e, proven R9); deferred per-lane l.
__global__ __launch_bounds__(256) void attn_flash(const bf16_t* __restrict__ qp,
                                                  const bf16_t* __restrict__ kp,
                                                  const bf16_t* __restrict__ vtp,
                                                  float* __restrict__ Opart,
                                                  float* __restrict__ mlpart) {
  const int id = blockIdx.x;
  const int bh = (id & 7) | (((id >> 3) & 1) << 3);
  const int qt = (id >> 4) & 31;
  const int half = id >> 9;
  const int pidx = (((qt << 4) | bh) << 1) + half;

  const int tid = threadIdx.x, w = tid >> 6, l = tid & 63;
  const int lr = l & 15, lg = l >> 4;
  const size_t hb = (size_t)bh * (SS * DH);
  const bf16_t* Q = qp + hb;
  const bf16_t* Kh = kp + hb;          // flat head block [2048 t][64 d]
  const bf16_t* Vth = vtp + hb;        // [32 tiles][8KB swizzled 64d x 64kv]

  __shared__ __align__(16) bf16_t KsL[2][4096];    // 16KB
  __shared__ __align__(16) bf16_t VtL[2][4096];    // 16KB  -> total 32KB

  const int qr0 = qt * 64 + w * 16;

  bf16x8 aq[2];
#pragma unroll
  for (int kc = 0; kc < 2; kc++)
    aq[kc] = *(const bf16x8*)(Q + (size_t)(qr0 + lr) * DH + kc * 32 + lg * 8);

  f32x4 o[4] = {};                    // O^T[d = n*16+lg*4+r][q = lr]
  float m_run = -1e30f, l_run = 0.f;  // log2-domain m; per-lane partial l

  // K staging source (pre-swizzled; chunk c = w*64+l -> row c>>3, slot (c&7)*16B,
  // src col-byte = slot ^ ((row&7)<<4); row&7 == l>>3)   [R7-proven]
  const int srow = (w << 3) + (l >> 3);
  const int scol = ((l & 7) ^ (l >> 3)) << 3;               // element offset
  const bf16_t* ks_it = Kh + (size_t)(half * 16) * 4096 + srow * 64 + scol;
  // V staging source: LINEAR copy of the pre-swizzled 8KB tile
  const bf16_t* vs_it = Vth + (size_t)(half * 16) * 4096 + (w * 64 + l) * 8;

  auto stage = [&](int buf) {
    char* kb = (char*)&KsL[buf][0];
    char* vb = (char*)&VtL[buf][0];
    __builtin_amdgcn_global_load_lds((const __attribute__((address_space(1))) void*)ks_it,
        (__attribute__((address_space(3))) void*)(kb + (w << 10)), 16, 0, 0);
    __builtin_amdgcn_global_load_lds((const __attribute__((address_space(1))) void*)(ks_it + 2048),
        (__attribute__((address_space(3))) void*)(kb + 4096 + (w << 10)), 16, 0, 0);
    __builtin_amdgcn_global_load_lds((const __attribute__((address_space(1))) void*)vs_it,
        (__attribute__((address_space(3))) void*)(vb + (w << 10)), 16, 0, 0);
    __builtin_amdgcn_global_load_lds((const __attribute__((address_space(1))) void*)(vs_it + 2048),
        (__attribute__((address_space(3))) void*)(vb + 4096 + (w << 10)), 16, 0, 0);
  };

  stage(0);

  for (int i = 0; i < 16; i++) {
    const int buf = i & 1;
    __syncthreads();                 // drains gloads of tile i -> buf ready
    if (i + 1 < 16) { ks_it += 4096; vs_it += 4096; stage(buf ^ 1); }

    // --- S^T = K @ Q^T : s[n][r] = S[kv=n*16+lg*4+r][q=lr] ---
    const char* ksb = (const char*)&KsL[buf][0];
    f32x4 s[4] = {};
    __builtin_amdgcn_s_setprio(1);
#pragma unroll
    for (int kc = 0; kc < 2; kc++) {
#pragma unroll
      for (int n = 0; n < 4; n++) {
        bf16x8 bk = *(const bf16x8*)(ksb + (n * 16 + lr) * 128 +
                                     ((kc * 64 + lg * 16) ^ ((lr & 7) << 4)));
        s[n] = __builtin_amdgcn_mfma_f32_16x16x32_bf16(bk, aq[kc], s[n], 0, 0, 0);
      }
    }
    __builtin_amdgcn_s_setprio(0);

    // --- in-lane online softmax, exp2 domain, defer-max (THR=8 in log2 units) ---
    float pmax = -1e30f;
#pragma unroll
    for (int n = 0; n < 4; n++)
#pragma unroll
      for (int r = 0; r < 4; r++) pmax = fmaxf(pmax, s[n][r]);
    pmax = fmaxf(pmax, __shfl_xor(pmax, 16));
    pmax = fmaxf(pmax, __shfl_xor(pmax, 32));
    if (!__all(pmax <= m_run + 8.0f)) {
      float mnew = fmaxf(m_run, pmax);
      float scale = exp2f(m_run - mnew);   // per-lane uniform (O^T layout)
      l_run *= scale;
#pragma unroll
      for (int n = 0; n < 4; n++)
#pragma unroll
        for (int r = 0; r < 4; r++) o[n][r] *= scale;
      m_run = mnew;
    }
    float rs = 0.f;
#pragma unroll
    for (int n = 0; n < 4; n++)
#pragma unroll
      for (int r = 0; r < 4; r++) {
        float e = exp2f(s[n][r] - m_run);
        s[n][r] = e;
        rs += e;
      }
    l_run += rs;                          // cross-lane sum deferred to end

    // --- PV from registers: o[n] += V^T(A) x P^T(B), 16x16x16 MFMA ---
    short4v pb[4];
#pragma unroll
    for (int c2 = 0; c2 < 4; c2++) {
      bf16x4 t;
#pragma unroll
      for (int r = 0; r < 4; r++) t[r] = (bf16_t)s[c2][r];
      pb[c2] = __builtin_bit_cast(short4v, t);
    }
    const char* vtb = (const char*)&VtL[buf][0];
    __builtin_amdgcn_s_setprio(1);
#pragma unroll
    for (int n = 0; n < 4; n++) {
#pragma unroll
      for (int c2 = 0; c2 < 4; c2++) {
        bf16x4 bvh = *(const bf16x4*)(vtb + (n * 16 + lr) * 128 +
                                      ((c2 * 32 + lg * 8) ^ ((lr & 7) << 4)));
        o[n] = __builtin_amdgcn_mfma_f32_16x16x16bf16_1k(
            __builtin_bit_cast(short4v, bvh), pb[c2], o[n], 0, 0, 0);
      }
    }
    __builtin_amdgcn_s_setprio(0);
  }

  // final cross-lane l reduction (deferred)
  l_run += __shfl_xor(l_run, 16);
  l_run += __shfl_xor(l_run, 32);

  // --- write partials: O^T lane-order (coalesced), m (log2-domain) / l per q-row ---
  float* ob = Opart + (size_t)pidx * 4096;
#pragma unroll
  for (int n = 0; n < 4; n++)
    *(f32x4*)(ob + ((w * 4 + n) * 64 + l) * 4) = o[n];
  if (lg == 0) {
    mlpart[(size_t)pidx * 128 + (w * 16 + lr) * 2 + 0] = m_run;
    mlpart[(size_t)pidx * 128 + (w * 16 + lr) * 2 + 1] = l_run;
  }
}

// ------------- combine the two KV-halves -> ctx (bf16); m's are log2-domain -------------
__global__ __launch_bounds__(256) void attn_combine(const float* __restrict__ Opart,
                                                    const float* __restrict__ mlpart,
                                                    bf16_t* __restrict__ ctx) {
  const int id = blockIdx.x;                 // 512 = qt*16 + bh
  const int qt = id >> 4, bh = id & 15;
  const int t = threadIdx.x, w = t >> 6, l = t & 63;
  const int lr = l & 15, lg = l >> 4;
  const int p0 = id * 2, p1 = id * 2 + 1;
  const int q = w * 16 + lr;

  float m1 = mlpart[(size_t)p0 * 128 + q * 2 + 0];
  float l1 = mlpart[(size_t)p0 * 128 + q * 2 + 1];
  float m2 = mlpart[(size_t)p1 * 128 + q * 2 + 0];
  float l2 = mlpart[(size_t)p1 * 128 + q * 2 + 1];
  float m = fmaxf(m1, m2);
  float e1 = exp2f(m1 - m), e2 = exp2f(m2 - m);
  float denom = (l1 * e1 + l2 * e2) * 8.0f;     // /sqrt(DH) after softmax
  float f1 = e1 / denom, f2 = e2 / denom;

  const int b = bh >> 3, h = bh & 7;
  const int trow = qt * 64 + q;
  size_t rowbase = ((size_t)b * SS + trow) * 512 + h * 64;

  const float* oa = Opart + (size_t)p0 * 4096;
  const float* obp = Opart + (size_t)p1 * 4096;
#pragma unroll
  for (int n = 0; n < 4; n++) {
    f32x4 a = *(const f32x4*)(oa + ((w * 4 + n) * 64 + l) * 4);
    f32x4 b2 = *(const f32x4*)(obp + ((w * 4 + n) * 64 + l) * 4);
    bf16x4 ov;
#pragma unroll
    for (int r = 0; r < 4; r++) ov[r] = (bf16_t)(a[r] * f1 + b2[r] * f2);
    *(bf16x4*)(&ctx[rowbase + n * 16 + lg * 4]) = ov;
  }
}

// ---------------- launcher ----------------
extern "C" void kernel_launch(void* const* d_in, const int* in_sizes, int n_in,
                              void* d_out, int out_size, void* d_ws, size_t ws_size,
                              hipStream_t stream) {
  const float* q  = (const float*)d_in[0];
  const float* k  = (const float*)d_in[1];
  const float* v  = (const float*)d_in[2];
  const float* Wq = (const float*)d_in[3];
  const float* bq = (const float*)d_in[4];
  const float* Wk = (const float*)d_in[5];
  const float* bk = (const float*)d_in[6];
  const float* Wv = (const float*)d_in[7];
  const float* bv = (const float*)d_in[8];
  const float* Wo = (const float*)d_in[9];
  const float* bo = (const float*)d_in[10];

  const size_t NQKV = (size_t)4096 * 512;   // 2,097,152 elems per tensor
  const size_t NW = (size_t)512 * 512;

  // ws layout (bf16 elems): [wt 4NW][proj qp,kp 2NQKV][vtp NQKV][ctx NQKV][qkvb 3NQKV ...]
  bf16_t* ws   = (bf16_t*)d_ws;
  bf16_t* wt   = ws;                 // 2 MB
  bf16_t* proj = wt + 4 * NW;        // 8 MB (qp, kp)
  bf16_t* vtp  = proj + 2 * NQKV;    // 4 MB (pre-swizzled V^T tiles per head)
  bf16_t* ctx  = vtp + NQKV;         // 4 MB
  bf16_t* qkvb = ctx + NQKV;         // 12 MB (dead after QKV GEMM)
  float* Opart  = (float*)qkvb;      // 16 MB  (1024 partials x 4096 f32)
  float* mlpart = Opart + (size_t)1024 * 4096;  // 0.5 MB

  // 1. cast q,k,v -> bf16 (z=0..2) + transpose+cast weights (z=3)
  prep<<<dim3(1024, 1, 4), 256, 0, stream>>>(q, k, v, Wq, Wk, Wv, Wo, qkvb, wt, (int)NQKV);
  // 2. fused QKV projections; Q pre-scaled by log2e; V scattered to swizzled V^T tiles
  gemm2<128, 64, 64, 32, 1, bf16_t><<<dim3(8, 32, 3), 256, 0, stream>>>(
      qkvb, wt, bq, bk, bv, proj, vtp, 4096, 512, 512, (long)NQKV, (long)NW, (long)NQKV, LOG2E);
  // 3. flash attention, KV-split x2 (1024 blocks, XCD-affine), all-gload staging
  attn_flash<<<1024, 256, 0, stream>>>(proj, proj + NQKV, vtp, Opart, mlpart);
  // 4. combine halves -> ctx
  attn_combine<<<512, 256, 0, stream>>>(Opart, mlpart, ctx);
  // 5. output projection (f32 out)
  gemm2<64, 64, 32, 32, 0, float><<<dim3(8, 64, 1), 256, 0, stream>>>(
      ctx, wt + 3 * NW, bo, bo, bo, (float*)d_out, nullptr, 4096, 512, 512, 0, 0, 0, 1.0f);
}

// Round 12
// 96.269 us; speedup vs baseline: 1.0408x; 1.0408x over previous
//
#include <hip/hip_runtime.h>
#include <hip/hip_bf16.h>

typedef __bf16 bf16_t;
typedef __bf16 bf16x8 __attribute__((ext_vector_type(8)));
typedef __bf16 bf16x4 __attribute__((ext_vector_type(4)));
typedef short short4v __attribute__((ext_vector_type(4)));
typedef float f32x4 __attribute__((ext_vector_type(4)));

static_assert(sizeof(bf16x8) == 16, "bf16x8 must be 16B");

// Problem constants
#define BB 2
#define SS 2048
#define DD 512
#define HH 8
#define DH 64
#define LOG2E 1.44269504088896f
// HID == 512; head block = contiguous [2048,64] at (b*8+h)*131072 (flat view).

// ------------- prep: z=0..2 cast q/k/v f32->bf16; z=3 transpose+cast weights -------------
__global__ void prep(const float* __restrict__ q, const float* __restrict__ k,
                     const float* __restrict__ v, const float* __restrict__ w0,
                     const float* __restrict__ w1, const float* __restrict__ w2,
                     const float* __restrict__ w3, bf16_t* __restrict__ qkvb,
                     bf16_t* __restrict__ wt, int n) {
  const int tid = threadIdx.x;
  if (blockIdx.z < 3) {
    const float* src = (blockIdx.z == 0) ? q : (blockIdx.z == 1) ? k : v;
    bf16_t* out = qkvb + (size_t)blockIdx.z * n;
    int i = (blockIdx.x * 256 + tid) * 8;
    if (i >= n) return;
    const float4* s4 = (const float4*)(src + i);
    float4 a = s4[0], b = s4[1];
    bf16x8 o;
    o[0] = (bf16_t)a.x; o[1] = (bf16_t)a.y; o[2] = (bf16_t)a.z; o[3] = (bf16_t)a.w;
    o[4] = (bf16_t)b.x; o[5] = (bf16_t)b.y; o[6] = (bf16_t)b.z; o[7] = (bf16_t)b.w;
    *(bf16x8*)(out + i) = o;
  } else {
    // transpose+cast: Wt[nn][kk] = (bf16)W[kk][nn]
    __shared__ float tile[32][33];
    const int x = blockIdx.x;                  // 0..1023
    const int wsel = x >> 8;
    const int nb = ((x >> 4) & 15) * 32, kb = (x & 15) * 32;
    const int tx = tid & 31, ty = tid >> 5;    // (32,8)
    const float* W = (wsel == 0) ? w0 : (wsel == 1) ? w1 : (wsel == 2) ? w2 : w3;
    bf16_t* out = wt + (size_t)wsel * 512 * 512;
#pragma unroll
    for (int i = 0; i < 4; i++)
      tile[ty + i * 8][tx] = W[(size_t)(kb + ty + i * 8) * 512 + nb + tx];
    __syncthreads();
#pragma unroll
    for (int i = 0; i < 4; i++)
      out[(size_t)(nb + ty + i * 8) * 512 + kb + tx] = (bf16_t)tile[tx][ty + i * 8];
  }
}

// ------------- GEMM: C[M,N] = (A[M,K] @ Bt[N,K]^T + bias[N]) * (z==0 ? s0 : 1) ----------
// Templated tile: BM x BN, BK=64, 256 thr, 4 waves 2x2. global_load_lds(16B), dbuf LDS.
// (R8-proven structure; TMODE scatter removed after the R11 regression.)
template <int BM, int BN, int WM, int WN, typename OutT>
__global__ __launch_bounds__(256) void gemm2(
    const bf16_t* __restrict__ Abase, const bf16_t* __restrict__ Btbase,
    const float* __restrict__ bias0, const float* __restrict__ bias1,
    const float* __restrict__ bias2, OutT* __restrict__ Cbase,
    int M, int N, int K, long Az, long Bz, long Cz, float scale0) {
  static_assert(BM == 2 * WM && BN == 2 * WN, "2x2 wave grid");
  constexpr int FM = WM / 16, FN = WN / 16;
  constexpr int AJ = BM / 32, BJ = BN / 32;

  const bf16_t* A  = Abase + (size_t)blockIdx.z * Az;
  const bf16_t* Bt = Btbase + (size_t)blockIdx.z * Bz;
  const float* bias = (blockIdx.z == 0) ? bias0 : (blockIdx.z == 1) ? bias1 : bias2;
  OutT* C = Cbase + (size_t)blockIdx.z * Cz;
  const float osc = (blockIdx.z == 0) ? scale0 : 1.0f;

  __shared__ bf16_t As[2][BM * 64];
  __shared__ bf16_t Bs[2][BN * 64];

  const int tid = threadIdx.x, w = tid >> 6, l = tid & 63;
  const int bm = blockIdx.y, bn = blockIdx.x;
  const int wm0 = (w >> 1) * WM, wn0 = (w & 1) * WN;
  const int lr = l & 15, lg = l >> 4;

  f32x4 acc[FM][FN] = {};

  auto stage = [&](int buf, int kt) {
#pragma unroll
    for (int j = 0; j < AJ; j++) {
      int lin = j * 256 + tid;              // 16B-chunk index
      int row = lin >> 3, cc = lin & 7;
      const bf16_t* g = A + (size_t)(bm * BM + row) * K + kt * 64 + cc * 8;
      __builtin_amdgcn_global_load_lds(
          (const __attribute__((address_space(1))) void*)g,
          (__attribute__((address_space(3))) void*)(&As[buf][(j * 256 + w * 64) * 8]), 16, 0, 0);
    }
#pragma unroll
    for (int j = 0; j < BJ; j++) {
      int lin = j * 256 + tid;
      int row = lin >> 3, cc = lin & 7;
      const bf16_t* g = Bt + (size_t)(bn * BN + row) * K + kt * 64 + cc * 8;
      __builtin_amdgcn_global_load_lds(
          (const __attribute__((address_space(1))) void*)g,
          (__attribute__((address_space(3))) void*)(&Bs[buf][(j * 256 + w * 64) * 8]), 16, 0, 0);
    }
  };

  stage(0, 0);
  const int KT = K >> 6;
  for (int kt = 0; kt < KT; kt++) {
    __syncthreads();                         // drains vmcnt -> buf[kt&1] ready
    if (kt + 1 < KT) stage((kt + 1) & 1, kt + 1);
    const bf16_t* as = As[kt & 1];
    const bf16_t* bs = Bs[kt & 1];
#pragma unroll
    for (int kc = 0; kc < 2; kc++) {
      bf16x8 a[FM], b[FN];
#pragma unroll
      for (int i = 0; i < FM; i++)
        a[i] = *(const bf16x8*)(as + (wm0 + i * 16 + lr) * 64 + kc * 32 + lg * 8);
#pragma unroll
      for (int j = 0; j < FN; j++)
        b[j] = *(const bf16x8*)(bs + (wn0 + j * 16 + lr) * 64 + kc * 32 + lg * 8);
#pragma unroll
      for (int i = 0; i < FM; i++)
#pragma unroll
        for (int j = 0; j < FN; j++)
          acc[i][j] = __builtin_amdgcn_mfma_f32_16x16x32_bf16(a[i], b[j], acc[i][j], 0, 0, 0);
    }
  }

  // epilogue: C row = (lane>>4)*4+reg, col = lane&15 (verified m89/m91 layout)
  const int row0 = bm * BM + wm0, col0 = bn * BN + wn0;
#pragma unroll
  for (int j = 0; j < FN; j++) {
    int col = col0 + j * 16 + lr;
    float bv = bias[col];
#pragma unroll
    for (int i = 0; i < FM; i++) {
      int row = row0 + i * 16 + lg * 4;
#pragma unroll
      for (int r = 0; r < 4; r++) {
        float vv = (acc[i][j][r] + bv) * osc;
        C[(size_t)(row + r) * N + col] = (OutT)vv;
      }
    }
  }
}

// ------------- flash attention, KV-split x2, 2-barrier software pipeline ----------
// grid 1024: id -> bh low3 (XCD-affinity), bh hi, qt, half. 4 waves, QBLK=64, KVBLK=64.
// Body T:  syncthreads(A)            -- K(T) gload + V(T) ds_writes visible
//          QK(T) issued (MFMA pipe)  -- reads KsL[T&1]
//          stage_k(T+1), load_v(T+1) -- async, consumed next body / end of body
//          softmax+PV(T-1) (VALU/DS) -- overlaps QK(T) MFMAs; reads VtL[(T-1)&1]
//          s_barrier(B)              -- all waves' PV reads done (no vmcnt drain)
//          write_v(T+1)              -- into VtL[(T+1)&1] == VtL[(T-1)&1], now safe
// K 2-deep / V 2-deep = 32KB total -> 4 blocks/CU (the R9 pipeline failed ONLY on
// its 40KB occupancy cliff; this is its clean test).
// Layouts verbatim R7/R8-proven; numerics verbatim R9-proven (exp2, deferred-l).
__global__ __launch_bounds__(256) void attn_flash(const bf16_t* __restrict__ qp,
                                                  const bf16_t* __restrict__ kp,
                                                  const bf16_t* __restrict__ vp,
                                                  float* __restrict__ Opart,
                                                  float* __restrict__ mlpart) {
  const int id = blockIdx.x;
  const int bh = (id & 7) | (((id >> 3) & 1) << 3);
  const int qt = (id >> 4) & 31;
  const int half = id >> 9;
  const int pidx = (((qt << 4) | bh) << 1) + half;

  const int tid = threadIdx.x, w = tid >> 6, l = tid & 63;
  const int lr = l & 15, lg = l >> 4;
  const size_t hb = (size_t)bh * (SS * DH);
  const bf16_t* Q = qp + hb;
  const bf16_t* Kh = kp + hb;
  const bf16_t* Vh = vp + hb;

  __shared__ __align__(16) bf16_t KsL[2][4096];    // 16KB
  __shared__ __align__(16) bf16_t VtL[2][4096];    // 16KB -> 32KB total

  const int qr0 = qt * 64 + w * 16;

  bf16x8 aq[2];
#pragma unroll
  for (int kc = 0; kc < 2; kc++)
    aq[kc] = *(const bf16x8*)(Q + (size_t)(qr0 + lr) * DH + kc * 32 + lg * 8);

  f32x4 o[4] = {};                    // O^T[d = n*16+lg*4+r][q = lr]
  float m_run = -1e30f, l_run = 0.f;  // log2-domain m; per-lane partial l

  // K staging source (pre-swizzled; R7-proven)
  const int krow = (w << 3) + (l >> 3);
  const int kcol = ((l & 7) ^ (l >> 3)) << 3;
  const bf16_t* ks_it = Kh + (size_t)(half * 16) * 4096 + krow * 64 + kcol;

  auto stage_k = [&](int buf, const bf16_t* ks) {
    char* kb = (char*)&KsL[buf][0];
    __builtin_amdgcn_global_load_lds((const __attribute__((address_space(1))) void*)ks,
        (__attribute__((address_space(3))) void*)(kb + (w << 10)), 16, 0, 0);
    __builtin_amdgcn_global_load_lds((const __attribute__((address_space(1))) void*)(ks + 2048),
        (__attribute__((address_space(3))) void*)(kb + 4096 + (w << 10)), 16, 0, 0);
  };

  // V staging (reg roundtrip, R7/R8-proven layout)
  const int vk0 = l, vd0 = w;
  const int vd1 = 4 + w;
  bf16x8 vreg0, vreg1;
  auto load_v = [&](int it) {
    const size_t kv0 = (size_t)it * 64;
    vreg0 = *(const bf16x8*)(Vh + (kv0 + vk0) * DH + vd0 * 8);
    vreg1 = *(const bf16x8*)(Vh + (kv0 + vk0) * DH + vd1 * 8);
  };
  auto write_v = [&](int buf) {
    char* vt = (char*)&VtL[buf][0];
#pragma unroll
    for (int j = 0; j < 8; j++) {
      int d0 = vd0 * 8 + j;                       // d0&7 == j
      *(bf16_t*)(vt + d0 * 128 + ((vk0 * 2) ^ (j << 4))) = vreg0[j];
    }
#pragma unroll
    for (int j = 0; j < 8; j++) {
      int d1 = vd1 * 8 + j;                       // d1&7 == j
      *(bf16_t*)(vt + d1 * 128 + ((vk0 * 2) ^ (j << 4))) = vreg1[j];
    }
  };

  const int it0 = half * 16;
  stage_k(0, ks_it);
  load_v(it0);
  write_v(0);

  f32x4 sA[4], sB[4];

#pragma unroll
  for (int T = 0; T <= 16; T++) {
    __syncthreads();                 // A: K(T) gload + V(T) writes visible

    // --- QK(T): issue early; executes on MFMA pipe during SM/PV(T-1) below ---
    if (T < 16) {
      f32x4* sc = (T & 1) ? sB : sA;
      const char* ksb = (const char*)&KsL[T & 1][0];
#pragma unroll
      for (int n = 0; n < 4; n++) sc[n] = f32x4{0.f, 0.f, 0.f, 0.f};
      __builtin_amdgcn_s_setprio(1);
#pragma unroll
      for (int kc = 0; kc < 2; kc++) {
#pragma unroll
        for (int n = 0; n < 4; n++) {
          bf16x8 bk = *(const bf16x8*)(ksb + (n * 16 + lr) * 128 +
                                       ((kc * 64 + lg * 16) ^ ((lr & 7) << 4)));
          sc[n] = __builtin_amdgcn_mfma_f32_16x16x32_bf16(bk, aq[kc], sc[n], 0, 0, 0);
        }
      }
      __builtin_amdgcn_s_setprio(0);
    }

    // --- async staging for tile T+1 (K gload_lds; V global->reg) ---
    if (T + 1 < 16) {
      ks_it += 4096;
      stage_k((T + 1) & 1, ks_it);
      load_v(it0 + T + 1);
    }

    // --- softmax + PV of tile T-1 (VALU/DS overlap with QK(T) MFMAs) ---
    if (T >= 1) {
      f32x4* sp = (T & 1) ? sA : sB;

      float pmax = -1e30f;
#pragma unroll
      for (int n = 0; n < 4; n++)
#pragma unroll
        for (int r = 0; r < 4; r++) pmax = fmaxf(pmax, sp[n][r]);
      pmax = fmaxf(pmax, __shfl_xor(pmax, 16));
      pmax = fmaxf(pmax, __shfl_xor(pmax, 32));
      if (!__all(pmax <= m_run + 8.0f)) {
        float mnew = fmaxf(m_run, pmax);
        float scale = exp2f(m_run - mnew);   // per-lane uniform (O^T layout)
        l_run *= scale;
#pragma unroll
        for (int n = 0; n < 4; n++)
#pragma unroll
          for (int r = 0; r < 4; r++) o[n][r] *= scale;
        m_run = mnew;
      }
      float rs = 0.f;
#pragma unroll
      for (int n = 0; n < 4; n++)
#pragma unroll
        for (int r = 0; r < 4; r++) {
          float e = exp2f(sp[n][r] - m_run);
          sp[n][r] = e;
          rs += e;
        }
      l_run += rs;                          // cross-lane sum deferred to end

      short4v pb[4];
#pragma unroll
      for (int c2 = 0; c2 < 4; c2++) {
        bf16x4 t;
#pragma unroll
        for (int r = 0; r < 4; r++) t[r] = (bf16_t)sp[c2][r];
        pb[c2] = __builtin_bit_cast(short4v, t);
      }
      const char* vtb = (const char*)&VtL[(T - 1) & 1][0];
      __builtin_amdgcn_s_setprio(1);
#pragma unroll
      for (int n = 0; n < 4; n++) {
#pragma unroll
        for (int c2 = 0; c2 < 4; c2++) {
          bf16x4 bvh = *(const bf16x4*)(vtb + (n * 16 + lr) * 128 +
                                        ((c2 * 32 + lg * 8) ^ ((lr & 7) << 4)));
          o[n] = __builtin_amdgcn_mfma_f32_16x16x16bf16_1k(
              __builtin_bit_cast(short4v, bvh), pb[c2], o[n], 0, 0, 0);
        }
      }
      __builtin_amdgcn_s_setprio(0);
    }

    // B: all waves' PV(T-1) LDS reads are complete (consumed by their MFMAs),
    // so VtL[(T+1)&1] (== VtL[(T-1)&1]) may be overwritten. No vmcnt drain.
    __builtin_amdgcn_s_barrier();
    if (T + 1 < 16) write_v((T + 1) & 1);
  }

  // final cross-lane l reduction (deferred)
  l_run += __shfl_xor(l_run, 16);
  l_run += __shfl_xor(l_run, 32);

  // --- write partials: O^T lane-order (coalesced), m (log2-domain) / l per q-row ---
  float* ob = Opart + (size_t)pidx * 4096;
#pragma unroll
  for (int n = 0; n < 4; n++)
    *(f32x4*)(ob + ((w * 4 + n) * 64 + l) * 4) = o[n];
  if (lg == 0) {
    mlpart[(size_t)pidx * 128 + (w * 16 + lr) * 2 + 0] = m_run;
    mlpart[(size_t)pidx * 128 + (w * 16 + lr) * 2 + 1] = l_run;
  }
}

// ------------- combine the two KV-halves -> ctx (bf16); m's are log2-domain -------------
__global__ __launch_bounds__(256) void attn_combine(const float* __restrict__ Opart,
                                                    const float* __restrict__ mlpart,
                                                    bf16_t* __restrict__ ctx) {
  const int id = blockIdx.x;                 // 512 = qt*16 + bh
  const int qt = id >> 4, bh = id & 15;
  const int t = threadIdx.x, w = t >> 6, l = t & 63;
  const int lr = l & 15, lg = l >> 4;
  const int p0 = id * 2, p1 = id * 2 + 1;
  const int q = w * 16 + lr;

  float m1 = mlpart[(size_t)p0 * 128 + q * 2 + 0];
  float l1 = mlpart[(size_t)p0 * 128 + q * 2 + 1];
  float m2 = mlpart[(size_t)p1 * 128 + q * 2 + 0];
  float l2 = mlpart[(size_t)p1 * 128 + q * 2 + 1];
  float m = fmaxf(m1, m2);
  float e1 = exp2f(m1 - m), e2 = exp2f(m2 - m);
  float denom = (l1 * e1 + l2 * e2) * 8.0f;     // /sqrt(DH) after softmax
  float f1 = e1 / denom, f2 = e2 / denom;

  const int b = bh >> 3, h = bh & 7;
  const int trow = qt * 64 + q;
  size_t rowbase = ((size_t)b * SS + trow) * 512 + h * 64;

  const float* oa = Opart + (size_t)p0 * 4096;
  const float* obp = Opart + (size_t)p1 * 4096;
#pragma unroll
  for (int n = 0; n < 4; n++) {
    f32x4 a = *(const f32x4*)(oa + ((w * 4 + n) * 64 + l) * 4);
    f32x4 b2 = *(const f32x4*)(obp + ((w * 4 + n) * 64 + l) * 4);
    bf16x4 ov;
#pragma unroll
    for (int r = 0; r < 4; r++) ov[r] = (bf16_t)(a[r] * f1 + b2[r] * f2);
    *(bf16x4*)(&ctx[rowbase + n * 16 + lg * 4]) = ov;
  }
}

// ---------------- launcher ----------------
extern "C" void kernel_launch(void* const* d_in, const int* in_sizes, int n_in,
                              void* d_out, int out_size, void* d_ws, size_t ws_size,
                              hipStream_t stream) {
  const float* q  = (const float*)d_in[0];
  const float* k  = (const float*)d_in[1];
  const float* v  = (const float*)d_in[2];
  const float* Wq = (const float*)d_in[3];
  const float* bq = (const float*)d_in[4];
  const float* Wk = (const float*)d_in[5];
  const float* bk = (const float*)d_in[6];
  const float* Wv = (const float*)d_in[7];
  const float* bv = (const float*)d_in[8];
  const float* Wo = (const float*)d_in[9];
  const float* bo = (const float*)d_in[10];

  const size_t NQKV = (size_t)4096 * 512;   // 2,097,152 elems per tensor
  const size_t NW = (size_t)512 * 512;

  // ws layout (bf16 elems): [wt 4NW][proj 3NQKV][ctx NQKV][qkvb 3NQKV ...]
  bf16_t* ws   = (bf16_t*)d_ws;
  bf16_t* wt   = ws;                 // 2 MB
  bf16_t* proj = wt + 4 * NW;        // 12 MB (qp, kp, vp)
  bf16_t* ctx  = proj + 3 * NQKV;    // 4 MB
  bf16_t* qkvb = ctx + NQKV;         // 12 MB (dead after QKV GEMM)
  float* Opart  = (float*)qkvb;      // 16 MB  (1024 partials x 4096 f32)
  float* mlpart = Opart + (size_t)1024 * 4096;  // 0.5 MB

  // 1. cast q,k,v -> bf16 (z=0..2) + transpose+cast weights (z=3)
  prep<<<dim3(1024, 1, 4), 256, 0, stream>>>(q, k, v, Wq, Wk, Wv, Wo, qkvb, wt, (int)NQKV);
  // 2. fused QKV projections; Q pre-scaled by log2e (exp2-domain softmax)
  gemm2<128, 64, 64, 32, bf16_t><<<dim3(8, 32, 3), 256, 0, stream>>>(
      qkvb, wt, bq, bk, bv, proj, 4096, 512, 512, (long)NQKV, (long)NW, (long)NQKV, LOG2E);
  // 3. flash attention, KV-split x2 (1024 blocks, XCD-affine), 2-barrier pipeline
  attn_flash<<<1024, 256, 0, stream>>>(proj, proj + NQKV, proj + 2 * NQKV, Opart, mlpart);
  // 4. combine halves -> ctx
  attn_combine<<<512, 256, 0, stream>>>(Opart, mlpart, ctx);
  // 5. output projection (f32 out)
  gemm2<64, 64, 32, 32, float><<<dim3(8, 64, 1), 256, 0, stream>>>(
      ctx, wt + 3 * NW, bo, bo, bo, (float*)d_out, 4096, 512, 512, 0, 0, 0, 1.0f);
}

// Round 13
// 92.278 us; speedup vs baseline: 1.0858x; 1.0433x over previous
//
#include <hip/hip_runtime.h>
#include <hip/hip_bf16.h>

typedef __bf16 bf16_t;
typedef __bf16 bf16x8 __attribute__((ext_vector_type(8)));
typedef __bf16 bf16x4 __attribute__((ext_vector_type(4)));
typedef short short4v __attribute__((ext_vector_type(4)));
typedef float f32x4 __attribute__((ext_vector_type(4)));

static_assert(sizeof(bf16x8) == 16, "bf16x8 must be 16B");

// Problem constants
#define BB 2
#define SS 2048
#define DD 512
#define HH 8
#define DH 64
#define LOG2E 1.44269504088896f
// HID == 512; head block = contiguous [2048,64] at (b*8+h)*131072 (flat view).

// ------------- prep: z=0..2 cast q/k/v f32->bf16; z=3 transpose+cast weights -------------
__global__ void prep(const float* __restrict__ q, const float* __restrict__ k,
                     const float* __restrict__ v, const float* __restrict__ w0,
                     const float* __restrict__ w1, const float* __restrict__ w2,
                     const float* __restrict__ w3, bf16_t* __restrict__ qkvb,
                     bf16_t* __restrict__ wt, int n) {
  const int tid = threadIdx.x;
  if (blockIdx.z < 3) {
    const float* src = (blockIdx.z == 0) ? q : (blockIdx.z == 1) ? k : v;
    bf16_t* out = qkvb + (size_t)blockIdx.z * n;
    int i = (blockIdx.x * 256 + tid) * 8;
    if (i >= n) return;
    const float4* s4 = (const float4*)(src + i);
    float4 a = s4[0], b = s4[1];
    bf16x8 o;
    o[0] = (bf16_t)a.x; o[1] = (bf16_t)a.y; o[2] = (bf16_t)a.z; o[3] = (bf16_t)a.w;
    o[4] = (bf16_t)b.x; o[5] = (bf16_t)b.y; o[6] = (bf16_t)b.z; o[7] = (bf16_t)b.w;
    *(bf16x8*)(out + i) = o;
  } else {
    // transpose+cast: Wt[nn][kk] = (bf16)W[kk][nn]
    __shared__ float tile[32][33];
    const int x = blockIdx.x;                  // 0..1023
    const int wsel = x >> 8;
    const int nb = ((x >> 4) & 15) * 32, kb = (x & 15) * 32;
    const int tx = tid & 31, ty = tid >> 5;    // (32,8)
    const float* W = (wsel == 0) ? w0 : (wsel == 1) ? w1 : (wsel == 2) ? w2 : w3;
    bf16_t* out = wt + (size_t)wsel * 512 * 512;
#pragma unroll
    for (int i = 0; i < 4; i++)
      tile[ty + i * 8][tx] = W[(size_t)(kb + ty + i * 8) * 512 + nb + tx];
    __syncthreads();
#pragma unroll
    for (int i = 0; i < 4; i++)
      out[(size_t)(nb + ty + i * 8) * 512 + kb + tx] = (bf16_t)tile[tx][ty + i * 8];
  }
}

// ------------- GEMM: C[M,N] = (A[M,K] @ Bt[N,K]^T + bias[N]) * (z==0 ? s0 : 1) ----------
// Templated tile: BM x BN, BK=64, 256 thr, 4 waves 2x2. global_load_lds(16B), dbuf LDS.
template <int BM, int BN, int WM, int WN, typename OutT>
__global__ __launch_bounds__(256) void gemm2(
    const bf16_t* __restrict__ Abase, const bf16_t* __restrict__ Btbase,
    const float* __restrict__ bias0, const float* __restrict__ bias1,
    const float* __restrict__ bias2, OutT* __restrict__ Cbase,
    int M, int N, int K, long Az, long Bz, long Cz, float scale0) {
  static_assert(BM == 2 * WM && BN == 2 * WN, "2x2 wave grid");
  constexpr int FM = WM / 16, FN = WN / 16;
  constexpr int AJ = BM / 32, BJ = BN / 32;

  const bf16_t* A  = Abase + (size_t)blockIdx.z * Az;
  const bf16_t* Bt = Btbase + (size_t)blockIdx.z * Bz;
  const float* bias = (blockIdx.z == 0) ? bias0 : (blockIdx.z == 1) ? bias1 : bias2;
  OutT* C = Cbase + (size_t)blockIdx.z * Cz;
  const float osc = (blockIdx.z == 0) ? scale0 : 1.0f;

  __shared__ bf16_t As[2][BM * 64];
  __shared__ bf16_t Bs[2][BN * 64];

  const int tid = threadIdx.x, w = tid >> 6, l = tid & 63;
  const int bm = blockIdx.y, bn = blockIdx.x;
  const int wm0 = (w >> 1) * WM, wn0 = (w & 1) * WN;
  const int lr = l & 15, lg = l >> 4;

  f32x4 acc[FM][FN] = {};

  auto stage = [&](int buf, int kt) {
#pragma unroll
    for (int j = 0; j < AJ; j++) {
      int lin = j * 256 + tid;              // 16B-chunk index
      int row = lin >> 3, cc = lin & 7;
      const bf16_t* g = A + (size_t)(bm * BM + row) * K + kt * 64 + cc * 8;
      __builtin_amdgcn_global_load_lds(
          (const __attribute__((address_space(1))) void*)g,
          (__attribute__((address_space(3))) void*)(&As[buf][(j * 256 + w * 64) * 8]), 16, 0, 0);
    }
#pragma unroll
    for (int j = 0; j < BJ; j++) {
      int lin = j * 256 + tid;
      int row = lin >> 3, cc = lin & 7;
      const bf16_t* g = Bt + (size_t)(bn * BN + row) * K + kt * 64 + cc * 8;
      __builtin_amdgcn_global_load_lds(
          (const __attribute__((address_space(1))) void*)g,
          (__attribute__((address_space(3))) void*)(&Bs[buf][(j * 256 + w * 64) * 8]), 16, 0, 0);
    }
  };

  stage(0, 0);
  const int KT = K >> 6;
  for (int kt = 0; kt < KT; kt++) {
    __syncthreads();                         // drains vmcnt -> buf[kt&1] ready
    if (kt + 1 < KT) stage((kt + 1) & 1, kt + 1);
    const bf16_t* as = As[kt & 1];
    const bf16_t* bs = Bs[kt & 1];
#pragma unroll
    for (int kc = 0; kc < 2; kc++) {
      bf16x8 a[FM], b[FN];
#pragma unroll
      for (int i = 0; i < FM; i++)
        a[i] = *(const bf16x8*)(as + (wm0 + i * 16 + lr) * 64 + kc * 32 + lg * 8);
#pragma unroll
      for (int j = 0; j < FN; j++)
        b[j] = *(const bf16x8*)(bs + (wn0 + j * 16 + lr) * 64 + kc * 32 + lg * 8);
#pragma unroll
      for (int i = 0; i < FM; i++)
#pragma unroll
        for (int j = 0; j < FN; j++)
          acc[i][j] = __builtin_amdgcn_mfma_f32_16x16x32_bf16(a[i], b[j], acc[i][j], 0, 0, 0);
    }
  }

  // epilogue: C row = (lane>>4)*4+reg, col = lane&15 (verified m89/m91 layout)
  const int row0 = bm * BM + wm0, col0 = bn * BN + wn0;
#pragma unroll
  for (int j = 0; j < FN; j++) {
    int col = col0 + j * 16 + lr;
    float bv = bias[col];
#pragma unroll
    for (int i = 0; i < FM; i++) {
      int row = row0 + i * 16 + lg * 4;
#pragma unroll
      for (int r = 0; r < 4; r++) {
        float vv = (acc[i][j][r] + bv) * osc;
        C[(size_t)(row + r) * N + col] = (OutT)vv;
      }
    }
  }
}

// ------------- flash attention, KV-split x2, in-block (q-half, kv-half) wave split ---------
// grid 1024: id -> bh low3 (XCD-affinity), bh hi, qt, half. 4 waves, QBLK=64, KVBLK=64.
// Wave w: q-half qh=w&1 (rows qt*64+qh*32 + qf*16+lr, qf=0,1), kv-half kh=w>>1
// (kv kh*32 + n*16 + ...). Each wave: 32q x 32kv per iter (same 1024 S/wave as R8)
// but reads ONLY its kv-half of K and V, and each fragment feeds 2 MFMAs (qf pair):
// LDS reads/wave-iter 24 instr/256B -> 12 instr/128B. Staging, swizzles, fragment
// address formulas, softmax numerics all verbatim R8/R11-proven. After the loop,
// kv-half wave pairs (w, w+2) merge (m,l,O) once through LDS scratch (element-
// aligned, no re-indexing), then waves 0,1 write the same Opart/mlpart format.
__global__ __launch_bounds__(256, 4) void attn_flash(const bf16_t* __restrict__ qp,
                                                     const bf16_t* __restrict__ kp,
                                                     const bf16_t* __restrict__ vp,
                                                     float* __restrict__ Opart,
                                                     float* __restrict__ mlpart) {
  const int id = blockIdx.x;
  const int bh = (id & 7) | (((id >> 3) & 1) << 3);
  const int qt = (id >> 4) & 31;
  const int half = id >> 9;
  const int pidx = (((qt << 4) | bh) << 1) + half;

  const int tid = threadIdx.x, w = tid >> 6, l = tid & 63;
  const int lr = l & 15, lg = l >> 4;
  const int qh = w & 1;                      // q-half of this wave
  const int kh = w >> 1;                     // kv-half of this wave
  const size_t hb = (size_t)bh * (SS * DH);
  const bf16_t* Q = qp + hb;
  const bf16_t* Kh = kp + hb;
  const bf16_t* Vh = vp + hb;

  __shared__ __align__(16) bf16_t KsL[2][4096];    // 16KB
  __shared__ __align__(16) bf16_t VtL[2][4096];    // 16KB -> 32KB total

  // Q fragments: 2 q-frags (rows qt*64 + qh*32 + qf*16 + lr)
  bf16x8 aq[2][2];
#pragma unroll
  for (int qf = 0; qf < 2; qf++)
#pragma unroll
    for (int kc = 0; kc < 2; kc++)
      aq[qf][kc] = *(const bf16x8*)(Q + (size_t)(qt * 64 + qh * 32 + qf * 16 + lr) * DH +
                                    kc * 32 + lg * 8);

  f32x4 o[2][4] = {};                   // O^T[d=n*16+lg*4+r][q], per qf, over OUR kv-half
  float m_run[2] = {-1e30f, -1e30f};    // log2-domain, per qf (q = ...+lr)
  float l_run[2] = {0.f, 0.f};          // per-lane partial (deferred reduction)

  // K staging source (pre-swizzled, R7-proven) — all threads stage the full tile
  const int krow = (w << 3) + (l >> 3);
  const int kcol = ((l & 7) ^ (l >> 3)) << 3;
  const bf16_t* ks_it = Kh + (size_t)(half * 16) * 4096 + krow * 64 + kcol;

  auto stage_k = [&](int buf, const bf16_t* ks) {
    char* kb = (char*)&KsL[buf][0];
    __builtin_amdgcn_global_load_lds((const __attribute__((address_space(1))) void*)ks,
        (__attribute__((address_space(3))) void*)(kb + (w << 10)), 16, 0, 0);
    __builtin_amdgcn_global_load_lds((const __attribute__((address_space(1))) void*)(ks + 2048),
        (__attribute__((address_space(3))) void*)(kb + 4096 + (w << 10)), 16, 0, 0);
  };

  // V staging (reg roundtrip, R7/R8-proven layout) — all threads stage the full tile
  const int vk0 = l, vd0 = w;
  const int vd1 = 4 + w;
  bf16x8 vreg0, vreg1;
  auto load_v = [&](int it) {
    const size_t kv0 = (size_t)it * 64;
    vreg0 = *(const bf16x8*)(Vh + (kv0 + vk0) * DH + vd0 * 8);
    vreg1 = *(const bf16x8*)(Vh + (kv0 + vk0) * DH + vd1 * 8);
  };
  auto write_v = [&](int buf) {
    char* vt = (char*)&VtL[buf][0];
#pragma unroll
    for (int j = 0; j < 8; j++) {
      int d0 = vd0 * 8 + j;
      *(bf16_t*)(vt + d0 * 128 + ((vk0 * 2) ^ (j << 4))) = vreg0[j];
    }
#pragma unroll
    for (int j = 0; j < 8; j++) {
      int d1 = vd1 * 8 + j;
      *(bf16_t*)(vt + d1 * 128 + ((vk0 * 2) ^ (j << 4))) = vreg1[j];
    }
  };

  const int it0 = half * 16;
  stage_k(0, ks_it);
  load_v(it0);
  write_v(0);

  for (int i = 0; i < 16; i++) {
    const int buf = i & 1;
    __syncthreads();                 // K(i) gload drained + V(i) writes visible
    if (i + 1 < 16) {
      ks_it += 4096;
      stage_k(buf ^ 1, ks_it);
      load_v(it0 + i + 1);
    }

    // --- S^T = K @ Q^T on OUR kv-half: s[qf][n][r] = S^T[kv=kh*32+n*16+lg*4+r][q] ---
    const char* ksb = (const char*)&KsL[buf][0];
    f32x4 s[2][2] = {};
    __builtin_amdgcn_s_setprio(1);
#pragma unroll
    for (int kc = 0; kc < 2; kc++) {
#pragma unroll
      for (int n = 0; n < 2; n++) {
        bf16x8 bk = *(const bf16x8*)(ksb + (kh * 32 + n * 16 + lr) * 128 +
                                     ((kc * 64 + lg * 16) ^ ((lr & 7) << 4)));
#pragma unroll
        for (int qf = 0; qf < 2; qf++)   // one K read feeds both q-frags
          s[qf][n] = __builtin_amdgcn_mfma_f32_16x16x32_bf16(bk, aq[qf][kc], s[qf][n], 0, 0, 0);
      }
    }
    __builtin_amdgcn_s_setprio(0);

    // --- in-lane online softmax per qf, exp2 domain, defer-max (THR=8) ---
#pragma unroll
    for (int qf = 0; qf < 2; qf++) {
      float pmax = -1e30f;
#pragma unroll
      for (int n = 0; n < 2; n++)
#pragma unroll
        for (int r = 0; r < 4; r++) pmax = fmaxf(pmax, s[qf][n][r]);
      pmax = fmaxf(pmax, __shfl_xor(pmax, 16));
      pmax = fmaxf(pmax, __shfl_xor(pmax, 32));
      if (!__all(pmax <= m_run[qf] + 8.0f)) {
        float mnew = fmaxf(m_run[qf], pmax);
        float scale = exp2f(m_run[qf] - mnew);   // per-lane uniform (O^T layout)
        l_run[qf] *= scale;
#pragma unroll
        for (int n = 0; n < 4; n++)
#pragma unroll
          for (int r = 0; r < 4; r++) o[qf][n][r] *= scale;
        m_run[qf] = mnew;
      }
      float rs = 0.f;
#pragma unroll
      for (int n = 0; n < 2; n++)
#pragma unroll
        for (int r = 0; r < 4; r++) {
          float e = exp2f(s[qf][n][r] - m_run[qf]);
          s[qf][n][r] = e;
          rs += e;
        }
      l_run[qf] += rs;                  // cross-lane sum deferred to end
    }

    // --- PV on OUR kv-half: o[qf][nd] += V^T(A) x P^T(B), 16x16x16 MFMA ---
    short4v pb[2][2];
#pragma unroll
    for (int qf = 0; qf < 2; qf++)
#pragma unroll
      for (int n = 0; n < 2; n++) {
        bf16x4 t;
#pragma unroll
        for (int r = 0; r < 4; r++) t[r] = (bf16_t)s[qf][n][r];
        pb[qf][n] = __builtin_bit_cast(short4v, t);
      }
    const char* vtb = (const char*)&VtL[buf][0];
    __builtin_amdgcn_s_setprio(1);
#pragma unroll
    for (int nd = 0; nd < 4; nd++) {
#pragma unroll
      for (int c2 = 0; c2 < 2; c2++) {
        bf16x4 bvh = *(const bf16x4*)(vtb + (nd * 16 + lr) * 128 +
                                      (((kh * 2 + c2) * 32 + lg * 8) ^ ((lr & 7) << 4)));
#pragma unroll
        for (int qf = 0; qf < 2; qf++)   // one V read feeds both q-frags
          o[qf][nd] = __builtin_amdgcn_mfma_f32_16x16x16bf16_1k(
              __builtin_bit_cast(short4v, bvh), pb[qf][c2], o[qf][nd], 0, 0, 0);
      }
    }
    __builtin_amdgcn_s_setprio(0);

    if (i + 1 < 16) write_v(buf ^ 1);
  }

  // in-wave deferred l reduction
#pragma unroll
  for (int qf = 0; qf < 2; qf++) {
    l_run[qf] += __shfl_xor(l_run[qf], 16);
    l_run[qf] += __shfl_xor(l_run[qf], 32);
  }

  // --- merge kv-halves across wave pairs (w, w+2) via LDS scratch (once) ---
  __syncthreads();                          // all LDS tile reads complete
  float* scrO = (float*)&KsL[0][0];         // 2 x 8KB (waves 2,3)
  float* scrM = (float*)&VtL[0][0];         // 2 x 1KB
  if (w >= 2) {
    float* po = scrO + (w - 2) * 2048;
#pragma unroll
    for (int qf = 0; qf < 2; qf++)
#pragma unroll
      for (int n = 0; n < 4; n++)
        *(f32x4*)(po + ((qf * 4 + n) * 64 + l) * 4) = o[qf][n];
    if (lg == 0) {
      float* pm = scrM + (w - 2) * 256;
#pragma unroll
      for (int qf = 0; qf < 2; qf++) {
        pm[qf * 32 + lr * 2 + 0] = m_run[qf];
        pm[qf * 32 + lr * 2 + 1] = l_run[qf];
      }
    }
  }
  __syncthreads();
  if (w < 2) {
    float* po = scrO + w * 2048;
    float* pm = scrM + w * 256;
    float* ob = Opart + (size_t)pidx * 4096;
#pragma unroll
    for (int qf = 0; qf < 2; qf++) {
      float mB = pm[qf * 32 + lr * 2 + 0];
      float lB = pm[qf * 32 + lr * 2 + 1];
      float mA = m_run[qf], lA = l_run[qf];
      float mM = fmaxf(mA, mB);
      float eA = exp2f(mA - mM), eB = exp2f(mB - mM);
      float lM = lA * eA + lB * eB;
      const int wg = w * 2 + qf;            // q = wg*16 + lr
#pragma unroll
      for (int n = 0; n < 4; n++) {
        f32x4 pv = *(const f32x4*)(po + ((qf * 4 + n) * 64 + l) * 4);
        f32x4 om;
#pragma unroll
        for (int r = 0; r < 4; r++) om[r] = o[qf][n][r] * eA + pv[r] * eB;
        *(f32x4*)(ob + ((wg * 4 + n) * 64 + l) * 4) = om;
      }
      if (lg == 0) {
        mlpart[(size_t)pidx * 128 + (wg * 16 + lr) * 2 + 0] = mM;
        mlpart[(size_t)pidx * 128 + (wg * 16 + lr) * 2 + 1] = lM;
      }
    }
  }
}

// ------------- combine the two KV-halves -> ctx (bf16); m's are log2-domain -------------
__global__ __launch_bounds__(256) void attn_combine(const float* __restrict__ Opart,
                                                    const float* __restrict__ mlpart,
                                                    bf16_t* __restrict__ ctx) {
  const int id = blockIdx.x;                 // 512 = qt*16 + bh
  const int qt = id >> 4, bh = id & 15;
  const int t = threadIdx.x, w = t >> 6, l = t & 63;
  const int lr = l & 15, lg = l >> 4;
  const int p0 = id * 2, p1 = id * 2 + 1;
  const int q = w * 16 + lr;

  float m1 = mlpart[(size_t)p0 * 128 + q * 2 + 0];
  float l1 = mlpart[(size_t)p0 * 128 + q * 2 + 1];
  float m2 = mlpart[(size_t)p1 * 128 + q * 2 + 0];
  float l2 = mlpart[(size_t)p1 * 128 + q * 2 + 1];
  float m = fmaxf(m1, m2);
  float e1 = exp2f(m1 - m), e2 = exp2f(m2 - m);
  float denom = (l1 * e1 + l2 * e2) * 8.0f;     // /sqrt(DH) after softmax
  float f1 = e1 / denom, f2 = e2 / denom;

  const int b = bh >> 3, h = bh & 7;
  const int trow = qt * 64 + q;
  size_t rowbase = ((size_t)b * SS + trow) * 512 + h * 64;

  const float* oa = Opart + (size_t)p0 * 4096;
  const float* obp = Opart + (size_t)p1 * 4096;
#pragma unroll
  for (int n = 0; n < 4; n++) {
    f32x4 a = *(const f32x4*)(oa + ((w * 4 + n) * 64 + l) * 4);
    f32x4 b2 = *(const f32x4*)(obp + ((w * 4 + n) * 64 + l) * 4);
    bf16x4 ov;
#pragma unroll
    for (int r = 0; r < 4; r++) ov[r] = (bf16_t)(a[r] * f1 + b2[r] * f2);
    *(bf16x4*)(&ctx[rowbase + n * 16 + lg * 4]) = ov;
  }
}

// ---------------- launcher ----------------
extern "C" void kernel_launch(void* const* d_in, const int* in_sizes, int n_in,
                              void* d_out, int out_size, void* d_ws, size_t ws_size,
                              hipStream_t stream) {
  const float* q  = (const float*)d_in[0];
  const float* k  = (const float*)d_in[1];
  const float* v  = (const float*)d_in[2];
  const float* Wq = (const float*)d_in[3];
  const float* bq = (const float*)d_in[4];
  const float* Wk = (const float*)d_in[5];
  const float* bk = (const float*)d_in[6];
  const float* Wv = (const float*)d_in[7];
  const float* bv = (const float*)d_in[8];
  const float* Wo = (const float*)d_in[9];
  const float* bo = (const float*)d_in[10];

  const size_t NQKV = (size_t)4096 * 512;   // 2,097,152 elems per tensor
  const size_t NW = (size_t)512 * 512;

  // ws layout (bf16 elems): [wt 4NW][proj 3NQKV][ctx NQKV][qkvb 3NQKV ...]
  bf16_t* ws   = (bf16_t*)d_ws;
  bf16_t* wt   = ws;                 // 2 MB
  bf16_t* proj = wt + 4 * NW;        // 12 MB (qp, kp, vp)
  bf16_t* ctx  = proj + 3 * NQKV;    // 4 MB
  bf16_t* qkvb = ctx + NQKV;         // 12 MB (dead after QKV GEMM)
  float* Opart  = (float*)qkvb;      // 16 MB  (1024 partials x 4096 f32)
  float* mlpart = Opart + (size_t)1024 * 4096;  // 0.5 MB

  // 1. cast q,k,v -> bf16 (z=0..2) + transpose+cast weights (z=3)
  prep<<<dim3(1024, 1, 4), 256, 0, stream>>>(q, k, v, Wq, Wk, Wv, Wo, qkvb, wt, (int)NQKV);
  // 2. fused QKV projections; Q pre-scaled by log2e (exp2-domain softmax)
  gemm2<128, 64, 64, 32, bf16_t><<<dim3(8, 32, 3), 256, 0, stream>>>(
      qkvb, wt, bq, bk, bv, proj, 4096, 512, 512, (long)NQKV, (long)NW, (long)NQKV, LOG2E);
  // 3. flash attention, KV-split x2 (1024 blocks, XCD-affine), in-block kv-split waves
  attn_flash<<<1024, 256, 0, stream>>>(proj, proj + NQKV, proj + 2 * NQKV, Opart, mlpart);
  // 4. combine halves -> ctx
  attn_combine<<<512, 256, 0, stream>>>(Opart, mlpart, ctx);
  // 5. output projection (f32 out)
  gemm2<64, 64, 32, 32, float><<<dim3(8, 64, 1), 256, 0, stream>>>(
      ctx, wt + 3 * NW, bo, bo, bo, (float*)d_out, 4096, 512, 512, 0, 0, 0, 1.0f);
}

// Round 14
// 91.141 us; speedup vs baseline: 1.0994x; 1.0125x over previous
//
#include <hip/hip_runtime.h>
#include <hip/hip_bf16.h>

typedef __bf16 bf16_t;
typedef __bf16 bf16x8 __attribute__((ext_vector_type(8)));
typedef __bf16 bf16x4 __attribute__((ext_vector_type(4)));
typedef short short4v __attribute__((ext_vector_type(4)));
typedef float f32x4 __attribute__((ext_vector_type(4)));

static_assert(sizeof(bf16x8) == 16, "bf16x8 must be 16B");

// Problem constants
#define BB 2
#define SS 2048
#define DD 512
#define HH 8
#define DH 64
#define LOG2E 1.44269504088896f
// HID == 512; head block = contiguous [2048,64] at (b*8+h)*131072 (flat view).

// ------------- prep: z=0..2 cast q/k/v f32->bf16; z=3 transpose+cast weights -------------
__global__ void prep(const float* __restrict__ q, const float* __restrict__ k,
                     const float* __restrict__ v, const float* __restrict__ w0,
                     const float* __restrict__ w1, const float* __restrict__ w2,
                     const float* __restrict__ w3, bf16_t* __restrict__ qkvb,
                     bf16_t* __restrict__ wt, int n) {
  const int tid = threadIdx.x;
  if (blockIdx.z < 3) {
    const float* src = (blockIdx.z == 0) ? q : (blockIdx.z == 1) ? k : v;
    bf16_t* out = qkvb + (size_t)blockIdx.z * n;
    int i = (blockIdx.x * 256 + tid) * 8;
    if (i >= n) return;
    const float4* s4 = (const float4*)(src + i);
    float4 a = s4[0], b = s4[1];
    bf16x8 o;
    o[0] = (bf16_t)a.x; o[1] = (bf16_t)a.y; o[2] = (bf16_t)a.z; o[3] = (bf16_t)a.w;
    o[4] = (bf16_t)b.x; o[5] = (bf16_t)b.y; o[6] = (bf16_t)b.z; o[7] = (bf16_t)b.w;
    *(bf16x8*)(out + i) = o;
  } else {
    // transpose+cast: Wt[nn][kk] = (bf16)W[kk][nn]
    __shared__ float tile[32][33];
    const int x = blockIdx.x;                  // 0..1023
    const int wsel = x >> 8;
    const int nb = ((x >> 4) & 15) * 32, kb = (x & 15) * 32;
    const int tx = tid & 31, ty = tid >> 5;    // (32,8)
    const float* W = (wsel == 0) ? w0 : (wsel == 1) ? w1 : (wsel == 2) ? w2 : w3;
    bf16_t* out = wt + (size_t)wsel * 512 * 512;
#pragma unroll
    for (int i = 0; i < 4; i++)
      tile[ty + i * 8][tx] = W[(size_t)(kb + ty + i * 8) * 512 + nb + tx];
    __syncthreads();
#pragma unroll
    for (int i = 0; i < 4; i++)
      out[(size_t)(nb + ty + i * 8) * 512 + kb + tx] = (bf16_t)tile[tx][ty + i * 8];
  }
}

// ------------- GEMM: C[M,N] = (A[M,K] @ Bt[N,K]^T + bias[N]) * (z==0 ? s0 : 1) ----------
// Templated tile: BM x BN, BK=64, 256 thr, 4 waves 2x2. global_load_lds(16B), dbuf LDS.
template <int BM, int BN, int WM, int WN, typename OutT>
__global__ __launch_bounds__(256) void gemm2(
    const bf16_t* __restrict__ Abase, const bf16_t* __restrict__ Btbase,
    const float* __restrict__ bias0, const float* __restrict__ bias1,
    const float* __restrict__ bias2, OutT* __restrict__ Cbase,
    int M, int N, int K, long Az, long Bz, long Cz, float scale0) {
  static_assert(BM == 2 * WM && BN == 2 * WN, "2x2 wave grid");
  constexpr int FM = WM / 16, FN = WN / 16;
  constexpr int AJ = BM / 32, BJ = BN / 32;

  const bf16_t* A  = Abase + (size_t)blockIdx.z * Az;
  const bf16_t* Bt = Btbase + (size_t)blockIdx.z * Bz;
  const float* bias = (blockIdx.z == 0) ? bias0 : (blockIdx.z == 1) ? bias1 : bias2;
  OutT* C = Cbase + (size_t)blockIdx.z * Cz;
  const float osc = (blockIdx.z == 0) ? scale0 : 1.0f;

  __shared__ bf16_t As[2][BM * 64];
  __shared__ bf16_t Bs[2][BN * 64];

  const int tid = threadIdx.x, w = tid >> 6, l = tid & 63;
  const int bm = blockIdx.y, bn = blockIdx.x;
  const int wm0 = (w >> 1) * WM, wn0 = (w & 1) * WN;
  const int lr = l & 15, lg = l >> 4;

  f32x4 acc[FM][FN] = {};

  auto stage = [&](int buf, int kt) {
#pragma unroll
    for (int j = 0; j < AJ; j++) {
      int lin = j * 256 + tid;              // 16B-chunk index
      int row = lin >> 3, cc = lin & 7;
      const bf16_t* g = A + (size_t)(bm * BM + row) * K + kt * 64 + cc * 8;
      __builtin_amdgcn_global_load_lds(
          (const __attribute__((address_space(1))) void*)g,
          (__attribute__((address_space(3))) void*)(&As[buf][(j * 256 + w * 64) * 8]), 16, 0, 0);
    }
#pragma unroll
    for (int j = 0; j < BJ; j++) {
      int lin = j * 256 + tid;
      int row = lin >> 3, cc = lin & 7;
      const bf16_t* g = Bt + (size_t)(bn * BN + row) * K + kt * 64 + cc * 8;
      __builtin_amdgcn_global_load_lds(
          (const __attribute__((address_space(1))) void*)g,
          (__attribute__((address_space(3))) void*)(&Bs[buf][(j * 256 + w * 64) * 8]), 16, 0, 0);
    }
  };

  stage(0, 0);
  const int KT = K >> 6;
  for (int kt = 0; kt < KT; kt++) {
    __syncthreads();                         // drains vmcnt -> buf[kt&1] ready
    if (kt + 1 < KT) stage((kt + 1) & 1, kt + 1);
    const bf16_t* as = As[kt & 1];
    const bf16_t* bs = Bs[kt & 1];
#pragma unroll
    for (int kc = 0; kc < 2; kc++) {
      bf16x8 a[FM], b[FN];
#pragma unroll
      for (int i = 0; i < FM; i++)
        a[i] = *(const bf16x8*)(as + (wm0 + i * 16 + lr) * 64 + kc * 32 + lg * 8);
#pragma unroll
      for (int j = 0; j < FN; j++)
        b[j] = *(const bf16x8*)(bs + (wn0 + j * 16 + lr) * 64 + kc * 32 + lg * 8);
#pragma unroll
      for (int i = 0; i < FM; i++)
#pragma unroll
        for (int j = 0; j < FN; j++)
          acc[i][j] = __builtin_amdgcn_mfma_f32_16x16x32_bf16(a[i], b[j], acc[i][j], 0, 0, 0);
    }
  }

  // epilogue: C row = (lane>>4)*4+reg, col = lane&15 (verified m89/m91 layout)
  const int row0 = bm * BM + wm0, col0 = bn * BN + wn0;
#pragma unroll
  for (int j = 0; j < FN; j++) {
    int col = col0 + j * 16 + lr;
    float bv = bias[col];
#pragma unroll
    for (int i = 0; i < FM; i++) {
      int row = row0 + i * 16 + lg * 4;
#pragma unroll
      for (int r = 0; r < 4; r++) {
        float vv = (acc[i][j][r] + bv) * osc;
        C[(size_t)(row + r) * N + col] = (OutT)vv;
      }
    }
  }
}

// ------------- flash attention, KV-split x4, KVBLK=32, 16KB LDS (8 blocks/CU) ---------
// grid 2048: id -> bh low3 (XCD-affinity), bh hi, qt, quarter. 4 waves, QBLK=64.
// Occupancy is the target: 16KB LDS x 8 blocks/CU = 32 waves/CU (was 16).
// All fragment/staging/swizzle formulas are the R7/R8-proven ones with the kv
// ranges halved; V^T rows are 64B with (d&7)<<3 swizzle (derived: residual
// conflict exactly 2-way = free). Partials stored bf16 (error ~1e-5 << 4.6e-4).
// exp2-domain softmax (Q pre-scaled by log2e), deferred per-lane l reduction.
__global__ __launch_bounds__(256, 8) void attn_flash(const bf16_t* __restrict__ qp,
                                                     const bf16_t* __restrict__ kp,
                                                     const bf16_t* __restrict__ vp,
                                                     bf16_t* __restrict__ Opart,
                                                     float* __restrict__ mlpart) {
  const int id = blockIdx.x;
  const int bh = (id & 7) | (((id >> 3) & 1) << 3);
  const int qt = (id >> 4) & 31;
  const int quarter = id >> 9;                    // 0..3
  const int pidx = (((qt << 4) | bh) << 2) + quarter;

  const int tid = threadIdx.x, w = tid >> 6, l = tid & 63;
  const int lr = l & 15, lg = l >> 4;
  const size_t hb = (size_t)bh * (SS * DH);
  const bf16_t* Q = qp + hb;
  const bf16_t* Kh = kp + hb;
  const bf16_t* Vh = vp + hb;

  __shared__ __align__(16) bf16_t KsL[2][2048];   // 2 x 4KB  [32 kv][64 d] swizzled
  __shared__ __align__(16) bf16_t VtL[2][2048];   // 2 x 4KB  [64 d][32 kv] swizzled

  const int qr0 = qt * 64 + w * 16;

  bf16x8 aq[2];
#pragma unroll
  for (int kc = 0; kc < 2; kc++)
    aq[kc] = *(const bf16x8*)(Q + (size_t)(qr0 + lr) * DH + kc * 32 + lg * 8);

  f32x4 o[4] = {};                    // O^T[d = n*16+lg*4+r][q = lr]
  float m_run = -1e30f, l_run = 0.f;  // log2-domain m; per-lane partial l

  // K staging: chunk c = tid -> row c>>3 (0..31), slot (c&7)*16B, pre-swizzled src
  const int krow = (w << 3) + (l >> 3);
  const int kcol = ((l & 7) ^ (l >> 3)) << 3;     // element offset
  const bf16_t* ks_it = Kh + (size_t)(quarter * 16) * 2048 + krow * 64 + kcol;

  auto stage_k = [&](int buf, const bf16_t* ks) {
    char* kb = (char*)&KsL[buf][0];
    __builtin_amdgcn_global_load_lds((const __attribute__((address_space(1))) void*)ks,
        (__attribute__((address_space(3))) void*)(kb + (w << 10)), 16, 0, 0);
  };

  // V staging (reg roundtrip): thread: kv = l&31, dv = (w<<1)|(l>>5) (0..7);
  // loads V[kv][dv*8..+8]; writes V^T[d][kv] at d*64 + ((kv*2) ^ ((d&7)<<3))
  const int vkv = l & 31;
  const int vdv = (w << 1) | (l >> 5);
  bf16x8 vreg;
  auto load_v = [&](int it) {                     // it = global 32-kv tile index
    vreg = *(const bf16x8*)(Vh + ((size_t)it * 32 + vkv) * DH + vdv * 8);
  };
  auto write_v = [&](int buf) {
    char* vt = (char*)&VtL[buf][0];
#pragma unroll
    for (int j = 0; j < 8; j++) {
      int d = vdv * 8 + j;                        // d&7 == j
      *(bf16_t*)(vt + d * 64 + ((vkv << 1) ^ (j << 3))) = vreg[j];
    }
  };

  const int it0 = quarter * 16;
  stage_k(0, ks_it);
  load_v(it0);
  write_v(0);

  for (int i = 0; i < 16; i++) {
    const int buf = i & 1;
    __syncthreads();                 // K(i) gload drained + V(i) writes visible
    if (i + 1 < 16) {
      ks_it += 2048;
      stage_k(buf ^ 1, ks_it);
      load_v(it0 + i + 1);
    }

    // --- S^T = K @ Q^T : s[n][r] = S^T[kv = n*16+lg*4+r][q = lr], n in {0,1} ---
    const char* ksb = (const char*)&KsL[buf][0];
    f32x4 s[2] = {};
    __builtin_amdgcn_s_setprio(1);
#pragma unroll
    for (int kc = 0; kc < 2; kc++) {
#pragma unroll
      for (int n = 0; n < 2; n++) {
        bf16x8 bk = *(const bf16x8*)(ksb + (n * 16 + lr) * 128 +
                                     ((kc * 64 + lg * 16) ^ ((lr & 7) << 4)));
        s[n] = __builtin_amdgcn_mfma_f32_16x16x32_bf16(bk, aq[kc], s[n], 0, 0, 0);
      }
    }
    __builtin_amdgcn_s_setprio(0);

    // --- in-lane online softmax, exp2 domain, defer-max (THR=8 log2 units) ---
    float pmax = -1e30f;
#pragma unroll
    for (int n = 0; n < 2; n++)
#pragma unroll
      for (int r = 0; r < 4; r++) pmax = fmaxf(pmax, s[n][r]);
    pmax = fmaxf(pmax, __shfl_xor(pmax, 16));
    pmax = fmaxf(pmax, __shfl_xor(pmax, 32));
    if (!__all(pmax <= m_run + 8.0f)) {
      float mnew = fmaxf(m_run, pmax);
      float scale = exp2f(m_run - mnew);   // per-lane uniform (O^T layout)
      l_run *= scale;
#pragma unroll
      for (int n = 0; n < 4; n++)
#pragma unroll
        for (int r = 0; r < 4; r++) o[n][r] *= scale;
      m_run = mnew;
    }
    float rs = 0.f;
#pragma unroll
    for (int n = 0; n < 2; n++)
#pragma unroll
      for (int r = 0; r < 4; r++) {
        float e = exp2f(s[n][r] - m_run);
        s[n][r] = e;
        rs += e;
      }
    l_run += rs;                          // cross-lane sum deferred to end

    // --- PV from registers: o[nd] += V^T(A) x P^T(B), 16x16x16 MFMA, c2 in {0,1} ---
    short4v pb[2];
#pragma unroll
    for (int c2 = 0; c2 < 2; c2++) {
      bf16x4 t;
#pragma unroll
      for (int r = 0; r < 4; r++) t[r] = (bf16_t)s[c2][r];
      pb[c2] = __builtin_bit_cast(short4v, t);
    }
    const char* vtb = (const char*)&VtL[buf][0];
    __builtin_amdgcn_s_setprio(1);
#pragma unroll
    for (int nd = 0; nd < 4; nd++) {
#pragma unroll
      for (int c2 = 0; c2 < 2; c2++) {
        bf16x4 bvh = *(const bf16x4*)(vtb + (nd * 16 + lr) * 64 +
                                      ((c2 * 32 + lg * 8) ^ ((lr & 7) << 3)));
        o[nd] = __builtin_amdgcn_mfma_f32_16x16x16bf16_1k(
            __builtin_bit_cast(short4v, bvh), pb[c2], o[nd], 0, 0, 0);
      }
    }
    __builtin_amdgcn_s_setprio(0);

    if (i + 1 < 16) write_v(buf ^ 1);
  }

  // final cross-lane l reduction (deferred)
  l_run += __shfl_xor(l_run, 16);
  l_run += __shfl_xor(l_run, 32);

  // --- write partials: O^T lane-order (coalesced) as bf16; m (log2) / l per q-row ---
  bf16_t* ob = Opart + (size_t)pidx * 4096;
#pragma unroll
  for (int n = 0; n < 4; n++) {
    bf16x4 t;
#pragma unroll
    for (int r = 0; r < 4; r++) t[r] = (bf16_t)o[n][r];
    *(bf16x4*)(ob + ((w * 4 + n) * 64 + l) * 4) = t;
  }
  if (lg == 0) {
    mlpart[(size_t)pidx * 128 + (w * 16 + lr) * 2 + 0] = m_run;
    mlpart[(size_t)pidx * 128 + (w * 16 + lr) * 2 + 1] = l_run;
  }
}

// ------------- combine the four KV-quarters -> ctx (bf16); m's are log2-domain -----------
__global__ __launch_bounds__(256) void attn_combine(const bf16_t* __restrict__ Opart,
                                                    const float* __restrict__ mlpart,
                                                    bf16_t* __restrict__ ctx) {
  const int gid = blockIdx.x;                // 512 = qt*16 + bh
  const int qt = gid >> 4, bh = gid & 15;
  const int t = threadIdx.x, w = t >> 6, l = t & 63;
  const int lr = l & 15, lg = l >> 4;
  const int q = w * 16 + lr;

  float mv[4], lv[4];
#pragma unroll
  for (int s = 0; s < 4; s++) {
    const float* ml = mlpart + (size_t)(gid * 4 + s) * 128 + q * 2;
    mv[s] = ml[0];
    lv[s] = ml[1];
  }
  float m = fmaxf(fmaxf(mv[0], mv[1]), fmaxf(mv[2], mv[3]));
  float e[4], denom = 0.f;
#pragma unroll
  for (int s = 0; s < 4; s++) { e[s] = exp2f(mv[s] - m); denom += lv[s] * e[s]; }
  denom *= 8.0f;                             // /sqrt(DH) applied after softmax
  float f[4];
#pragma unroll
  for (int s = 0; s < 4; s++) f[s] = e[s] / denom;

  const int b = bh >> 3, h = bh & 7;
  const int trow = qt * 64 + q;
  size_t rowbase = ((size_t)b * SS + trow) * 512 + h * 64;

#pragma unroll
  for (int n = 0; n < 4; n++) {
    float acc[4] = {0.f, 0.f, 0.f, 0.f};
#pragma unroll
    for (int s = 0; s < 4; s++) {
      bf16x4 v = *(const bf16x4*)(Opart + (size_t)(gid * 4 + s) * 4096 +
                                  ((w * 4 + n) * 64 + l) * 4);
#pragma unroll
      for (int r = 0; r < 4; r++) acc[r] += (float)v[r] * f[s];
    }
    bf16x4 ov;
#pragma unroll
    for (int r = 0; r < 4; r++) ov[r] = (bf16_t)acc[r];
    *(bf16x4*)(&ctx[rowbase + n * 16 + lg * 4]) = ov;
  }
}

// ---------------- launcher ----------------
extern "C" void kernel_launch(void* const* d_in, const int* in_sizes, int n_in,
                              void* d_out, int out_size, void* d_ws, size_t ws_size,
                              hipStream_t stream) {
  const float* q  = (const float*)d_in[0];
  const float* k  = (const float*)d_in[1];
  const float* v  = (const float*)d_in[2];
  const float* Wq = (const float*)d_in[3];
  const float* bq = (const float*)d_in[4];
  const float* Wk = (const float*)d_in[5];
  const float* bk = (const float*)d_in[6];
  const float* Wv = (const float*)d_in[7];
  const float* bv = (const float*)d_in[8];
  const float* Wo = (const float*)d_in[9];
  const float* bo = (const float*)d_in[10];

  const size_t NQKV = (size_t)4096 * 512;   // 2,097,152 elems per tensor
  const size_t NW = (size_t)512 * 512;

  // ws layout (bf16 elems): [wt 4NW][proj 3NQKV][ctx NQKV][qkvb 3NQKV ...]
  // Opart (bf16, 16MB) + mlpart (1MB) overlap qkvb (dead after the QKV GEMM).
  bf16_t* ws   = (bf16_t*)d_ws;
  bf16_t* wt   = ws;                 // 2 MB
  bf16_t* proj = wt + 4 * NW;        // 12 MB (qp, kp, vp)
  bf16_t* ctx  = proj + 3 * NQKV;    // 4 MB
  bf16_t* qkvb = ctx + NQKV;         // 12 MB (dead after QKV GEMM)
  bf16_t* Opart = qkvb;              // 16 MB  (2048 partials x 4096 bf16)
  float* mlpart = (float*)(Opart + (size_t)2048 * 4096);  // 1 MB

  // 1. cast q,k,v -> bf16 (z=0..2) + transpose+cast weights (z=3)
  prep<<<dim3(1024, 1, 4), 256, 0, stream>>>(q, k, v, Wq, Wk, Wv, Wo, qkvb, wt, (int)NQKV);
  // 2. fused QKV projections; Q pre-scaled by log2e (exp2-domain softmax)
  gemm2<128, 64, 64, 32, bf16_t><<<dim3(8, 32, 3), 256, 0, stream>>>(
      qkvb, wt, bq, bk, bv, proj, 4096, 512, 512, (long)NQKV, (long)NW, (long)NQKV, LOG2E);
  // 3. flash attention, KV-split x4 (2048 blocks = 8/CU, XCD-affine), 16KB LDS
  attn_flash<<<2048, 256, 0, stream>>>(proj, proj + NQKV, proj + 2 * NQKV, Opart, mlpart);
  // 4. combine quarters -> ctx
  attn_combine<<<512, 256, 0, stream>>>(Opart, mlpart, ctx);
  // 5. output projection (f32 out)
  gemm2<64, 64, 32, 32, float><<<dim3(8, 64, 1), 256, 0, stream>>>(
      ctx, wt + 3 * NW, bo, bo, bo, (float*)d_out, 4096, 512, 512, 0, 0, 0, 1.0f);
}